// Round 11
// baseline (85.713 us; speedup 1.0000x reference)
//
#include <hip/hip_runtime.h>
#include <hip/hip_bf16.h>

// Problem constants (from setup_inputs): price_data float32 [64, 4096, 64]
#define B 64
#define S 4096
#define C 64
#define NCHUNK 32            // s-chunks per batch in K1; block = (b, chunk)
#define LCH (S / NCHUNK)     // 128 s per K1 block
#define SPT (LCH / 16)       // 8 s per thread-slice (16 slices per block)

// native clang vector type (usable with __builtin_nontemporal_store)
typedef float f32x4 __attribute__((ext_vector_type(4)));

// Partials in ws: part[p][ (b*NCHUNK + chunk)*64 + c ], p: 0=sum 1=sumsq
// 2=gain 3=loss 4=sum12 5=sum26
#define PSTRIDE ((size_t)B * NCHUNK * 64)   // 131072 floats per plane (3 MB total)

__device__ inline f32x4 vmax0(f32x4 a) {
    f32x4 r;
    r.x = fmaxf(a.x, 0.f);
    r.y = fmaxf(a.y, 0.f);
    r.z = fmaxf(a.z, 0.f);
    r.w = fmaxf(a.w, 0.f);
    return r;
}

// K1: PURE partial reduction (64 MB linear read -> 3 MB partials). 2048 blocks
// x 256 threads. tid = slice*16 + c4; 16B/lane coalesced loads. No stores to
// out: keeps this a pure read stream and leaves the input L3-resident for K2.
__global__ __launch_bounds__(256) void ti_reduce(const f32x4* __restrict__ in4,
                                                 float* __restrict__ part) {
    const int b     = blockIdx.x / NCHUNK;
    const int chunk = blockIdx.x % NCHUNK;
    const int tid   = threadIdx.x;
    const int sl    = tid >> 4;     // s-slice 0..15
    const int c4    = tid & 15;     // float4 channel group 0..15
    const int s0    = chunk * LCH + sl * SPT;

    const size_t rowbase = (size_t)b * S;

    f32x4 acc[6];
    #pragma unroll
    for (int p = 0; p < 6; ++p) acc[p] = (f32x4){0.f, 0.f, 0.f, 0.f};

    f32x4 prev = (f32x4){0.f, 0.f, 0.f, 0.f};
    if (s0 > 0) prev = in4[(rowbase + s0 - 1) * 16 + c4];

    #pragma unroll
    for (int j = 0; j < SPT; ++j) {
        const int s = s0 + j;
        const f32x4 v = in4[(rowbase + s) * 16 + c4];
        acc[0] += v;
        acc[1] += v * v;
        if (s > 0) {
            const f32x4 d = v - prev;
            acc[2] += vmax0(d);
            acc[3] += vmax0(-d);
        }
        prev = v;
        if (s >= S - 26) {
            acc[5] += v;
            if (s >= S - 12) acc[4] += v;
        }
    }

    // Cross-slice reduce in LDS: lds[p][sl][ch]
    __shared__ float lds[6][16][64];
    #pragma unroll
    for (int p = 0; p < 6; ++p) *(f32x4*)&lds[p][sl][c4 * 4] = acc[p];
    __syncthreads();

    if (tid < 64) {
        const size_t idx = ((size_t)(b * NCHUNK + chunk)) * 64 + tid;
        #pragma unroll
        for (int p = 0; p < 6; ++p) {
            float t = 0.f;
            #pragma unroll
            for (int s2 = 0; s2 < 16; ++s2) t += lds[p][s2][tid];
            part[(size_t)p * PSTRIDE + idx] = t;
        }
    }
}

// K2: full-row writer with LDS-staged sources. 2048 blocks x 256 threads;
// block = (b, 128-row segment). Phase 0 stages the block's 32 KB of input
// (L3-resident) into LDS and builds the 1 KB stats row-template; phase 1
// writes the block's 160 KB output span as one perfectly linear NT store
// stream with ZERO interleaved global loads (every source is an LDS read).
__global__ __launch_bounds__(256) void ti_write(const f32x4* __restrict__ in4,
                                                const float* __restrict__ part,
                                                f32x4* __restrict__ out4) {
    const int blk  = blockIdx.x;
    const int b    = blk >> 5;          // 0..63
    const int seg  = blk & 31;          // 0..31 (128 rows each)
    const int tid  = threadIdx.x;

    __shared__ f32x4 lin[128 * 16];     // 32 KB: staged input rows
    __shared__ f32x4 lst[64];           // 1 KB: stats row template (f4 16..79)
    __shared__ float sums[6][64];       // 1.5 KB

    // ---- phase 0a: stage input rows (linear, coalesced, L3 hits) ----
    const size_t in_base = ((size_t)b * S + (size_t)seg * 128) * 16;
    #pragma unroll
    for (int k = tid; k < 128 * 16; k += 256)
        lin[k] = in4[in_base + k];

    // ---- phase 0b: fold partials for this b -> stats row template ----
    {
        const int w    = tid >> 6;      // wave 0..3
        const int lane = tid & 63;
        float a = 0.f;
        #pragma unroll
        for (int ch = 0; ch < NCHUNK; ++ch)
            a += part[(size_t)w * PSTRIDE + (size_t)(b * NCHUNK + ch) * 64 + lane];
        sums[w][lane] = a;
        if (w < 2) {
            const int p1 = 4 + w;
            float a2 = 0.f;
            #pragma unroll
            for (int ch = 0; ch < NCHUNK; ++ch)
                a2 += part[(size_t)p1 * PSTRIDE + (size_t)(b * NCHUNK + ch) * 64 + lane];
            sums[p1][lane] = a2;
        }
    }
    __syncthreads();

    if (tid < 64) {
        const float sum = sums[0][tid], sumsq = sums[1][tid];
        const float gain = sums[2][tid], loss = sums[3][tid];
        const float s12 = sums[4][tid], s26 = sums[5][tid];

        const float inv_sm1 = 1.f / (float)(S - 1);
        const float ag = gain * inv_sm1;
        const float al = loss * inv_sm1;
        const float rs = ag / (al + 1e-7f);
        const float rsi = 100.f - 100.f / (1.f + rs);

        const float macd = s12 * (1.f / 12.f) - s26 * (1.f / 26.f);

        const float sma = sum * (1.f / (float)S);
        const float var = sumsq * (1.f / (float)S) - sma * sma;
        const float sd = sqrtf(fmaxf(var, 0.f));

        // template entry j = which*16 + c4 holds channels c4*4..+3 of stat
        // 'which'; lst laid out so out f4 index q maps to lst[q-16].
        float* lstf = (float*)lst;      // lstf[which*64 + c]
        lstf[0 * 64 + tid] = rsi;
        lstf[1 * 64 + tid] = macd;
        lstf[2 * 64 + tid] = sma + 2.f * sd;
        lstf[3 * 64 + tid] = sma - 2.f * sd;
    }
    __syncthreads();

    // ---- phase 1: linear full-row NT store stream (160 KB per block) ----
    // flat f4 index f = it*256 + tid over [0, 10240); row = f/80, q = f%80.
    // Incremental (row,q) bookkeeping: +256 f4 == +3 rows +16 q.
    const size_t out_base = ((size_t)b * S + (size_t)seg * 128) * 80;
    int row = tid / 80;                 // one divide at entry (0..3)
    int q   = tid - row * 80;           // 0..79

    #pragma unroll 8
    for (int it = 0; it < 40; ++it) {
        const f32x4 v = (q < 16) ? lin[(row << 4) + q] : lst[q - 16];
        __builtin_nontemporal_store(v, &out4[out_base + (size_t)it * 256 + tid]);
        q += 16;
        row += 3;
        if (q >= 80) { q -= 80; row += 1; }
    }
}

extern "C" void kernel_launch(void* const* d_in, const int* in_sizes, int n_in,
                              void* d_out, int out_size, void* d_ws, size_t ws_size,
                              hipStream_t stream) {
    const f32x4* in4 = (const f32x4*)d_in[0];
    f32x4* out4 = (f32x4*)d_out;
    float* part = (float*)d_ws;            // 6 * 131072 floats = 3 MB

    ti_reduce<<<B * NCHUNK, 256, 0, stream>>>(in4, part);
    ti_write<<<B * 32, 256, 0, stream>>>(in4, part, out4);
}

// Round 12
// 79.122 us; speedup vs baseline: 1.0833x; 1.0833x over previous
//
#include <hip/hip_runtime.h>
#include <hip/hip_bf16.h>

// Problem constants (from setup_inputs): price_data float32 [64, 4096, 64]
#define B 64
#define S 4096
#define C 64
#define NCHUNK 16            // s-chunks per batch in K1; block = (b, chunk)
#define LCH (S / NCHUNK)     // 256 s per K1 block
#define RW (LCH / 4)         // 64 rows per wave (4 waves per block)

// native clang vector type (usable with __builtin_nontemporal_store)
typedef float f32x4 __attribute__((ext_vector_type(4)));

// Partials in ws: part[p][ (b*NCHUNK + chunk)*64 + c ], p: 0=sum 1=sumsq
// 2=gain 3=loss 4=sum12 5=sum26
#define PSTRIDE ((size_t)B * NCHUNK * 64)   // 65536 floats per plane (1.5 MB total)

__device__ inline f32x4 vmax0(f32x4 a) {
    f32x4 r;
    r.x = fmaxf(a.x, 0.f);
    r.y = fmaxf(a.y, 0.f);
    r.z = fmaxf(a.z, 0.f);
    r.w = fmaxf(a.w, 0.f);
    return r;
}

__device__ inline f32x4 shfl4(f32x4 v, int src) {
    f32x4 r;
    r.x = __shfl(v.x, src);
    r.y = __shfl(v.y, src);
    r.z = __shfl(v.z, src);
    r.w = __shfl(v.w, src);
    return r;
}

// K1: fused input-copy + partial reductions, wave-contiguous load shape.
// Lane = r*16 + c4 (r = 4 CONSECUTIVE rows, c4 = f4 channel group): each wave
// load is ONE contiguous 1KB segment (copy-ubench shape); stores are 4x256B
// at tight 1280B stride. Delta x[s]-x[s-1] via __shfl: lane-16 = previous row
// in-group; lane 48+c4 of previous iteration = group boundary.
__global__ __launch_bounds__(256) void ti_copy_reduce(const f32x4* __restrict__ in4,
                                                      f32x4* __restrict__ out4,
                                                      float* __restrict__ part) {
    const int b     = blockIdx.x / NCHUNK;
    const int chunk = blockIdx.x % NCHUNK;
    const int tid   = threadIdx.x;
    const int w     = tid >> 6;     // wave 0..3
    const int lane  = tid & 63;
    const int r     = lane >> 4;    // row-in-group 0..3
    const int c4    = lane & 15;    // f4 channel group 0..15
    const int wbase = chunk * LCH + w * RW;   // wave's first row

    const size_t rowbase = (size_t)b * S;

    f32x4 acc[6];
    #pragma unroll
    for (int p = 0; p < 6; ++p) acc[p] = (f32x4){0.f, 0.f, 0.f, 0.f};

    // value of row (wbase-1), channels c4*4..+3 — consumed by r==0 lanes
    f32x4 prev_top = (f32x4){0.f, 0.f, 0.f, 0.f};
    if (wbase > 0) prev_top = in4[(rowbase + wbase - 1) * 16 + c4];

    #pragma unroll 4
    for (int i = 0; i < RW / 4; ++i) {          // 16 iterations
        const int s = wbase + i * 4 + r;        // this lane's row
        const f32x4 v = in4[(rowbase + wbase + i * 4) * 16 + lane]; // 1KB/wave
        __builtin_nontemporal_store(v, &out4[(rowbase + s) * 80 + c4]);

        acc[0] += v;
        acc[1] += v * v;

        f32x4 pv = shfl4(v, lane - 16);         // previous row (r>=1)
        if (r == 0) pv = prev_top;
        if (s > 0) {
            const f32x4 d = v - pv;
            acc[2] += vmax0(d);
            acc[3] += vmax0(-d);
        }
        prev_top = shfl4(v, 48 + c4);           // group's last row, next iter

        if (s >= S - 26) {
            acc[5] += v;
            if (s >= S - 12) acc[4] += v;
        }
    }

    // Cross-slice reduce in LDS: lds[p][sl][ch], sl = tid>>4 = w*4+r
    __shared__ float lds[6][16][64];
    const int sl = tid >> 4;
    #pragma unroll
    for (int p = 0; p < 6; ++p) *(f32x4*)&lds[p][sl][c4 * 4] = acc[p];
    __syncthreads();

    if (tid < 64) {
        const size_t idx = ((size_t)(b * NCHUNK + chunk)) * 64 + tid;
        #pragma unroll
        for (int p = 0; p < 6; ++p) {
            float t = 0.f;
            #pragma unroll
            for (int s2 = 0; s2 < 16; ++s2) t += lds[p][s2][tid];
            part[(size_t)p * PSTRIDE + idx] = t;
        }
    }
}

// K2: fold partials -> stats (redundantly per block) + broadcast channels
// [64,320). 2048 blocks x 256 threads; block = (b, 128-row segment).
// NT stores (r8 A/B: plain stores cost ~10 us on this stream). Verbatim r6/r10.
__global__ __launch_bounds__(256) void ti_stats_broadcast(const float* __restrict__ part,
                                                          f32x4* __restrict__ out4) {
    const int blk  = blockIdx.x;
    const int b    = blk >> 5;          // 0..63
    const int seg  = blk & 31;          // 0..31 (128 rows each)
    const int tid  = threadIdx.x;
    const int w    = tid >> 6;          // wave 0..3
    const int lane = tid & 63;

    __shared__ float sums[6][64];
    __shared__ f32x4 st4[4][16];

    // ---- fold partials for this b: plane w (+ planes 4,5 on waves 0,1) ----
    {
        float a = 0.f;
        #pragma unroll
        for (int ch = 0; ch < NCHUNK; ++ch)
            a += part[(size_t)w * PSTRIDE + (size_t)(b * NCHUNK + ch) * 64 + lane];
        sums[w][lane] = a;
        if (w < 2) {
            const int p1 = 4 + w;
            float a2 = 0.f;
            #pragma unroll
            for (int ch = 0; ch < NCHUNK; ++ch)
                a2 += part[(size_t)p1 * PSTRIDE + (size_t)(b * NCHUNK + ch) * 64 + lane];
            sums[p1][lane] = a2;
        }
    }
    __syncthreads();

    if (tid < 64) {
        const float sum = sums[0][tid], sumsq = sums[1][tid];
        const float gain = sums[2][tid], loss = sums[3][tid];
        const float s12 = sums[4][tid], s26 = sums[5][tid];

        const float inv_sm1 = 1.f / (float)(S - 1);
        const float ag = gain * inv_sm1;
        const float al = loss * inv_sm1;
        const float rs = ag / (al + 1e-7f);
        const float rsi = 100.f - 100.f / (1.f + rs);

        const float macd = s12 * (1.f / 12.f) - s26 * (1.f / 26.f);

        const float sma = sum * (1.f / (float)S);
        const float var = sumsq * (1.f / (float)S) - sma * sma;
        const float sd = sqrtf(fmaxf(var, 0.f));

        float* stf = (float*)st4;   // stf[which*64 + c]
        stf[0 * 64 + tid] = rsi;
        stf[1 * 64 + tid] = macd;
        stf[2 * 64 + tid] = sma + 2.f * sd;
        stf[3 * 64 + tid] = sma - 2.f * sd;
    }
    __syncthreads();

    // ---- broadcast channels [64,320) for 128 rows, NT 1KB/wave runs ----
    const int q = lane;                 // 0..63, loop-invariant
    const f32x4 v = st4[q >> 4][q & 15];

    const size_t base_row = (size_t)b * S + (size_t)seg * 128;
    #pragma unroll 8
    for (int pass = 0; pass < 32; ++pass) {
        const size_t row = base_row + pass * 4 + w;   // 1KB contiguous per wave
        __builtin_nontemporal_store(v, &out4[row * 80 + 16 + q]);
    }
}

extern "C" void kernel_launch(void* const* d_in, const int* in_sizes, int n_in,
                              void* d_out, int out_size, void* d_ws, size_t ws_size,
                              hipStream_t stream) {
    const f32x4* in4 = (const f32x4*)d_in[0];
    f32x4* out4 = (f32x4*)d_out;
    float* part = (float*)d_ws;            // 6 * 65536 floats = 1.5 MB

    ti_copy_reduce<<<B * NCHUNK, 256, 0, stream>>>(in4, out4, part);
    ti_stats_broadcast<<<B * 32, 256, 0, stream>>>(part, out4);
}